// Round 6
// baseline (58.769 us; speedup 1.0000x reference)
//
#include <hip/hip_runtime.h>

// Problem constants (fixed by the reference).
constexpr int kN = 2048;
constexpr int kB = 16;
constexpr int kNB = 128;  // NUM_BUCKETS
constexpr int kR = 4;     // rows per block (divides kN -> no batch crossing)

// fl32(ln2) = 0x3F317218 — what any f32 log chain divides by (log(2.0f)).
#define LN2_BITS 0x3f317218u

// Native vector types (HIP's float4/int4 are classes; nontemporal builtin
// needs a true vector type).
typedef float f32x4 __attribute__((ext_vector_type(4)));
typedef int   i32x4 __attribute__((ext_vector_type(4)));

// ---------------------------------------------------------------------------
// Bucket matching the all-f32 arbiter chain with correctly-rounded f32 log
// (verified absmax 0.0 in R3/R5 — DO NOT TOUCH):
//   bk = clip( floorf( fl32( CRlog32(a) / fl32(ln2) ) ), 0, 128 ), a = max(|dt|,1)
// Fast path 31-clz(a) is provably identical outside narrow windows around 2^j;
// inside, emulate with (float)log((double)a) + IEEE f32 divide.
// ---------------------------------------------------------------------------
__device__ __forceinline__ int bucket_of(int rowts, int tj) {
    int dt = rowts - tj;
    unsigned a = (unsigned)(dt < 0 ? -dt : dt);
    a = a < 1u ? 1u : a;                   // a in [1, 10^7) < 2^24
    int k = 31 - __clz((int)a);            // exact floor(log2(a))
    unsigned p = 1u << k;
    unsigned Wlo = ((p >> 20) * (unsigned)k) + 8u;
    unsigned Whi = ((p >> 19) * (unsigned)(k + 1)) + 8u;
    bool danger = ((a - p) < Wlo) | (((p << 1) - a) < Whi);
    if (!danger) return k;
    float L = (float)log((double)a);       // correctly-rounded f32 log(a)
    float q = L / __uint_as_float(LN2_BITS);  // IEEE f32 divide (no fast-math)
    int bk = (int)floorf(q);
    return bk < 0 ? 0 : (bk > kNB ? kNB : bk);
}

// ---------------------------------------------------------------------------
// Fused kernel, kR rows per block:
//   blocks [0, B*N/kR)            : kR consecutive ts-bias rows (same batch b)
//   blocks [B*N/kR, (B*N+N)/kR)   : kR consecutive pos-bias rows
// Per ts block: stage ts_w once, load each column int4 once and reuse it for
// all kR rows (amortizes LDS stage + column loads; 4x fewer block cold-starts).
// Output is write-once and bigger than L3 -> nontemporal stores.
// ---------------------------------------------------------------------------
__global__ __launch_bounds__(256) void bias_kernel(const int* __restrict__ ts,
                                                   const float* __restrict__ pos_w,
                                                   const float* __restrict__ ts_w,
                                                   float* __restrict__ out) {
    const int blk = blockIdx.x;
    constexpr int kTsBlocks = kB * kN / kR;   // 8192

    if (blk < kTsBlocks) {
        // ---- bucketized timestamp bias rows [blk*kR, blk*kR + kR) ----
        __shared__ float w[kNB + 1];
        if (threadIdx.x <= kNB) w[threadIdx.x] = ts_w[threadIdx.x];
        __syncthreads();

        const int row0 = blk * kR;              // global ts-row index b*kN + i0
        const int b    = row0 >> 11;            // / kN
        const int i0   = row0 & (kN - 1);
        const int* __restrict__ tsrow = ts + (size_t)b * kN;

        int rowts[kR];
        #pragma unroll
        for (int r = 0; r < kR; ++r)
            rowts[r] = tsrow[min(i0 + r + 1, kN - 1)];

        const i32x4* __restrict__ ts4 = (const i32x4*)tsrow;
        f32x4* __restrict__ obase4 =
            (f32x4*)(out + (size_t)kN * kN + (size_t)row0 * kN);

        #pragma unroll
        for (int kk = 0; kk < kN / (4 * 256); ++kk) {
            const int v = kk * 256 + threadIdx.x;
            const i32x4 t4 = ts4[v];            // loaded once, reused kR times
            #pragma unroll
            for (int r = 0; r < kR; ++r) {
                f32x4 res;
                res.x = w[bucket_of(rowts[r], t4.x)];
                res.y = w[bucket_of(rowts[r], t4.y)];
                res.z = w[bucket_of(rowts[r], t4.z)];
                res.w = w[bucket_of(rowts[r], t4.w)];
                __builtin_nontemporal_store(res, &obase4[r * (kN / 4) + v]);
            }
        }
    } else {
        // ---- relative position bias rows: out[i][j] = pos_w[N-1-i + j] ----
        const int i0 = (blk - kTsBlocks) * kR;
        #pragma unroll
        for (int kk = 0; kk < kN / (4 * 256); ++kk) {
            const int v = kk * 256 + threadIdx.x;
            #pragma unroll
            for (int r = 0; r < kR; ++r) {
                const float* __restrict__ src = pos_w + (kN - 1 - (i0 + r));
                f32x4 res;
                res.x = src[4 * v + 0];
                res.y = src[4 * v + 1];
                res.z = src[4 * v + 2];
                res.w = src[4 * v + 3];
                __builtin_nontemporal_store(
                    res, (f32x4*)(out + (size_t)(i0 + r) * kN) + v);
            }
        }
    }
}

extern "C" void kernel_launch(void* const* d_in, const int* in_sizes, int n_in,
                              void* d_out, int out_size, void* d_ws, size_t ws_size,
                              hipStream_t stream) {
    const int*   all_ts = (const int*)d_in[0];    // (B, N) int32
    const float* pos_w  = (const float*)d_in[1];  // (2N-1,) f32
    const float* ts_w   = (const float*)d_in[2];  // (NB+1,) f32
    float* out = (float*)d_out;                   // [N*N] pos ++ [B*N*N] ts

    bias_kernel<<<(kB * kN + kN) / kR, 256, 0, stream>>>(all_ts, pos_w, ts_w, out);
}